// Round 2
// baseline (341.597 us; speedup 1.0000x reference)
//
#include <hip/hip_runtime.h>
#include <math.h>

#define N_NODES 100000
#define N_EDGES 1600000
#define F 128
#define NBUCK 196        // buckets of 512 rows
#define EPB 4096         // edges per bucketize block
#define CAP 9216         // fixed bucket region capacity (avg 8192, +11 sigma)

typedef _Float16 f16x2 __attribute__((ext_vector_type(2)));
typedef _Float16 f16x8 __attribute__((ext_vector_type(8)));
typedef __fp16 fp16x2 __attribute__((ext_vector_type(2)));
typedef float f32x2 __attribute__((ext_vector_type(2)));
typedef float f32x4 __attribute__((ext_vector_type(4)));

__device__ inline uint pkrtz(float a, float b) {
    union { fp16x2 h; uint u; } c;
    c.h = __builtin_amdgcn_cvt_pkrtz(a, b);
    return c.u;
}
__device__ inline f16x2 as2(uint u) {
    union { uint u; f16x2 h; } c; c.u = u; return c.h;
}

__device__ inline int wave_incl_scan(int v, int lane) {
#pragma unroll
    for (int off = 1; off < 64; off <<= 1) {
        int t = __shfl_up(v, off);
        if (lane >= off) v += t;
    }
    return v;
}

// ---------------- CSR build: single-pass bucket sort, fixed regions ----------------

__global__ __launch_bounds__(256) void bucketize_kernel(const int* __restrict__ row,
                                                        const int* __restrict__ col,
                                                        int* __restrict__ bucket_cursor,
                                                        int* __restrict__ pairs) {
    __shared__ int stage[EPB];
    __shared__ unsigned char bid[EPB];
    __shared__ int lcnt[NBUCK], lcur[NBUCK], loff[NBUCK], gbase[NBUCK];
    __shared__ int wsum[4];
    const int tid = threadIdx.x;
    const int lane = tid & 63;
    const int wid = tid >> 6;
    const int base = blockIdx.x * EPB;
    const int cnt = min(N_EDGES - base, EPB);

    for (int i = tid; i < NBUCK; i += 256) { lcnt[i] = 0; lcur[i] = 0; }
    __syncthreads();
    for (int i = 0; i < EPB / 256; ++i) {
        int e = base + i * 256 + tid;
        if (e < N_EDGES) atomicAdd(&lcnt[row[e] >> 9], 1);
    }
    __syncthreads();
    {   // exclusive scan of lcnt -> loff (wave scan + 4-wave combine)
        int v = (tid < NBUCK) ? lcnt[tid] : 0;
        int inc = wave_incl_scan(v, lane);
        if (lane == 63) wsum[wid] = inc;
        __syncthreads();
        if (tid == 0) {
            int a = 0;
#pragma unroll
            for (int i = 0; i < 4; ++i) { int t = wsum[i]; wsum[i] = a; a += t; }
        }
        __syncthreads();
        if (tid < NBUCK) loff[tid] = inc - v + wsum[wid];
    }
    if (tid < NBUCK) {
        int c = lcnt[tid];
        gbase[tid] = c ? atomicAdd(&bucket_cursor[tid], c) : 0;
    }
    __syncthreads();
    for (int i = 0; i < EPB / 256; ++i) {
        int e = base + i * 256 + tid;
        if (e < N_EDGES) {
            int r = row[e], c = col[e];
            int b = r >> 9;
            int rk = atomicAdd(&lcur[b], 1);
            int q = loff[b] + rk;
            stage[q] = ((r & 511) << 17) | c;   // 9b local row | 17b col
            bid[q] = (unsigned char)b;
        }
    }
    __syncthreads();
    for (int q = tid; q < cnt; q += 256) {
        int b = bid[q];
        int t = gbase[b] + (q - loff[b]);
        if (t < CAP) pairs[b * CAP + t] = stage[q];
    }
}

__global__ __launch_bounds__(512) void csr_finalize_kernel(const int* __restrict__ pairs,
                                                           const int* __restrict__ bucket_cursor,
                                                           int* __restrict__ csr_col,
                                                           int2* __restrict__ rs,
                                                           float* __restrict__ deg_inv) {
    __shared__ int rcnt[512], rcnt2[512], roff[512];
    __shared__ int colstage[CAP];
    __shared__ int wsum[8];
    const int tid = threadIdx.x;
    const int lane = tid & 63;
    const int wid = tid >> 6;
    const int b = blockIdx.x;
    const int cnt = min(bucket_cursor[b], CAP);
    const int base = b * CAP;
    const int* reg = &pairs[base];

    rcnt[tid] = 0;
    rcnt2[tid] = 0;
    __syncthreads();
    for (int q = tid; q < cnt; q += 512) atomicAdd(&rcnt[reg[q] >> 17], 1);
    __syncthreads();
    const int d = rcnt[tid];
    int inc = wave_incl_scan(d, lane);
    if (lane == 63) wsum[wid] = inc;
    __syncthreads();
    if (tid == 0) {
        int a = 0;
#pragma unroll
        for (int i = 0; i < 8; ++i) { int t = wsum[i]; wsum[i] = a; a += t; }
    }
    __syncthreads();
    const int excl = inc - d + wsum[wid];
    roff[tid] = excl;
    const int grow = (b << 9) + tid;
    if (grow < N_NODES) {
        rs[grow] = make_int2(base + excl, d);
        deg_inv[grow] = d ? 1.0f / (float)d : 0.0f;
    }
    __syncthreads();
    for (int q = tid; q < cnt; q += 512) {
        int v = reg[q];
        int lr = v >> 17;
        int rk = atomicAdd(&rcnt2[lr], 1);
        colstage[roff[lr] + rk] = v & 0x1FFFF;
    }
    __syncthreads();
    for (int q = tid; q < cnt; q += 512) csr_col[base + q] = colstage[q];
}

// ---------------- conversions ----------------

__global__ __launch_bounds__(256) void convert_w_kernel(const float* __restrict__ W1,
                                                        const float* __restrict__ W2,
                                                        uint* __restrict__ W1h,
                                                        uint* __restrict__ W2h) {
    int i = blockIdx.x * 256 + threadIdx.x;   // pair index
    if (i < F * F / 2) {
        float2 a = *(const float2*)&W1[i * 2];
        float2 b = *(const float2*)&W2[i * 2];
        W1h[i] = pkrtz(a.x, a.y);
        W2h[i] = pkrtz(b.x, b.y);
    }
}

// X f32 -> f16, 8 floats per thread (replaces gemm1's f32 staging pass)
__global__ __launch_bounds__(256) void convert_x_kernel(const float* __restrict__ X,
                                                        uint* __restrict__ Xh) {
    int i = blockIdx.x * 256 + threadIdx.x;   // chunk of 8 floats
    if (i < N_NODES * F / 8) {
        float4 a = *(const float4*)&X[(size_t)i * 8];
        float4 b = *(const float4*)&X[(size_t)i * 8 + 4];
        uint4 o = {pkrtz(a.x, a.y), pkrtz(a.z, a.w), pkrtz(b.x, b.y), pkrtz(b.z, b.w)};
        *(uint4*)&Xh[(size_t)i * 4] = o;
    }
}

// ---------------- fused mean-agg + MFMA GEMM ----------------
// Legality: D^-1 A (H W^T + 1 b^T) = (D^-1 A H) W^T + mask.b^T  (mask = deg>0,
// deg-0 rows aggregate to 0). So each layer = gather-agg(H) -> GEMM.
// Block = 256 thr = 4 waves = 64 output rows. Wave w owns EXACTLY rows
// 16w..16w+15: quarter-wave qw in [4w,4w+3] aggregates rows 4qw..4qw+3 into
// xs (f16, pitch 136), then the same wave reads its own rows as A-frags ->
// intra-wave LDS ordering, NO barrier between gather and MFMA. Waves drift
// independently; MFMA of early waves hides gather latency of late waves.
// Gather: 8-edge batches (8 cols then 8 independent uint4 loads in flight).
// Single __syncthreads guards the xs -> ys (f32 epilogue transpose) overlay.

template <bool ELU, bool OUT_F32>
__global__ __launch_bounds__(256, 4) void fused_agg_gemm_kernel(
        const ushort* __restrict__ H,
        const int2* __restrict__ rs,
        const int* __restrict__ csr_col,
        const float* __restrict__ deg_inv,
        const ushort* __restrict__ Wh,
        const float* __restrict__ bias,
        void* __restrict__ out) {
    __shared__ __align__(16) char smraw[4 * 16 * 132 * 4];  // 33792 B
    ushort* xs = (ushort*)smraw;                     // [64][136] f16 agg rows
    float (*ys)[16][132] = (float(*)[16][132])smraw; // [4][16][132] f32

    const int tid = threadIdx.x;
    const int m0 = blockIdx.x << 6;
    const int qw = tid >> 4;          // quarter-wave id 0..15
    const int fo = (tid & 15) << 3;   // ushort feature offset (8 f16 per lane)

    // ---- phase A: gather-aggregate 4 rows per quarter-wave ----
    for (int rr = 0; rr < 4; ++rr) {
        const int rowi = qw * 4 + rr;
        const int node = m0 + rowi;
        f32x2 a[4];
#pragma unroll
        for (int i = 0; i < 4; ++i) a[i] = (f32x2){0.f, 0.f};
        float di = 0.f;
        if (node < N_NODES) {
            const int2 sd = rs[node];
            int p = sd.x;
            const int e = sd.x + sd.y;
            di = deg_inv[node];
            while (p + 7 < e) {   // 8-edge batch: 8 cols, then 8 rows in flight
                int cc[8];
#pragma unroll
                for (int k = 0; k < 8; ++k) cc[k] = __builtin_nontemporal_load(&csr_col[p + k]);
                uint4 vv[8];
#pragma unroll
                for (int k = 0; k < 8; ++k) vv[k] = *(const uint4*)&H[(size_t)cc[k] * F + fo];
#pragma unroll
                for (int k = 0; k < 8; k += 4) {
                    f16x2 h0 = (as2(vv[k].x) + as2(vv[k + 1].x)) + (as2(vv[k + 2].x) + as2(vv[k + 3].x));
                    f16x2 h1 = (as2(vv[k].y) + as2(vv[k + 1].y)) + (as2(vv[k + 2].y) + as2(vv[k + 3].y));
                    f16x2 h2 = (as2(vv[k].z) + as2(vv[k + 1].z)) + (as2(vv[k + 2].z) + as2(vv[k + 3].z));
                    f16x2 h3 = (as2(vv[k].w) + as2(vv[k + 1].w)) + (as2(vv[k + 2].w) + as2(vv[k + 3].w));
                    a[0] += (f32x2){(float)h0.x, (float)h0.y};
                    a[1] += (f32x2){(float)h1.x, (float)h1.y};
                    a[2] += (f32x2){(float)h2.x, (float)h2.y};
                    a[3] += (f32x2){(float)h3.x, (float)h3.y};
                }
                p += 8;
            }
            if (p + 3 < e) {
                int c0 = csr_col[p], c1 = csr_col[p + 1], c2 = csr_col[p + 2], c3 = csr_col[p + 3];
                uint4 v0 = *(const uint4*)&H[(size_t)c0 * F + fo];
                uint4 v1 = *(const uint4*)&H[(size_t)c1 * F + fo];
                uint4 v2 = *(const uint4*)&H[(size_t)c2 * F + fo];
                uint4 v3 = *(const uint4*)&H[(size_t)c3 * F + fo];
                f16x2 h0 = (as2(v0.x) + as2(v1.x)) + (as2(v2.x) + as2(v3.x));
                f16x2 h1 = (as2(v0.y) + as2(v1.y)) + (as2(v2.y) + as2(v3.y));
                f16x2 h2 = (as2(v0.z) + as2(v1.z)) + (as2(v2.z) + as2(v3.z));
                f16x2 h3 = (as2(v0.w) + as2(v1.w)) + (as2(v2.w) + as2(v3.w));
                a[0] += (f32x2){(float)h0.x, (float)h0.y};
                a[1] += (f32x2){(float)h1.x, (float)h1.y};
                a[2] += (f32x2){(float)h2.x, (float)h2.y};
                a[3] += (f32x2){(float)h3.x, (float)h3.y};
                p += 4;
            }
            if (p + 1 < e) {
                int c0 = csr_col[p], c1 = csr_col[p + 1];
                uint4 v0 = *(const uint4*)&H[(size_t)c0 * F + fo];
                uint4 v1 = *(const uint4*)&H[(size_t)c1 * F + fo];
                f16x2 h0 = as2(v0.x) + as2(v1.x);
                f16x2 h1 = as2(v0.y) + as2(v1.y);
                f16x2 h2 = as2(v0.z) + as2(v1.z);
                f16x2 h3 = as2(v0.w) + as2(v1.w);
                a[0] += (f32x2){(float)h0.x, (float)h0.y};
                a[1] += (f32x2){(float)h1.x, (float)h1.y};
                a[2] += (f32x2){(float)h2.x, (float)h2.y};
                a[3] += (f32x2){(float)h3.x, (float)h3.y};
                p += 2;
            }
            if (p < e) {
                int c = csr_col[p];
                uint4 v = *(const uint4*)&H[(size_t)c * F + fo];
                f16x2 h0 = as2(v.x), h1 = as2(v.y), h2 = as2(v.z), h3 = as2(v.w);
                a[0] += (f32x2){(float)h0.x, (float)h0.y};
                a[1] += (f32x2){(float)h1.x, (float)h1.y};
                a[2] += (f32x2){(float)h2.x, (float)h2.y};
                a[3] += (f32x2){(float)h3.x, (float)h3.y};
            }
        }
        uint4 o = {pkrtz(a[0].x * di, a[0].y * di), pkrtz(a[1].x * di, a[1].y * di),
                   pkrtz(a[2].x * di, a[2].y * di), pkrtz(a[3].x * di, a[3].y * di)};
        *(uint4*)&xs[rowi * 136 + fo] = o;
    }
    // NO barrier: wave w wrote rows 16w..16w+15 and reads only those as A-frags.

    // ---- phase B: MFMA Y = g @ W^T ----
    const int w = tid >> 6;
    const int lane = tid & 63;
    const int q = lane >> 4;
    const int t = lane & 15;

    f16x8 afr[4];
#pragma unroll
    for (int kk = 0; kk < 4; ++kk)
        afr[kk] = *(const f16x8*)&xs[(w * 16 + t) * 136 + kk * 32 + q * 8];

    f32x4 acc[8];
#pragma unroll
    for (int j = 0; j < 8; ++j) acc[j] = (f32x4){0.f, 0.f, 0.f, 0.f};

#pragma unroll
    for (int j = 0; j < 8; ++j) {
        const ushort* wrow = &Wh[(j * 16 + t) * F + q * 8];
#pragma unroll
        for (int kk = 0; kk < 4; ++kk) {
            f16x8 bfr = *(const f16x8*)&wrow[kk * 32];
            acc[j] = __builtin_amdgcn_mfma_f32_16x16x32_f16(afr[kk], bfr, acc[j], 0, 0, 0);
        }
    }

    __syncthreads();  // all waves done reading xs; overlay with ys

    // epilogue: masked bias (deg>0), optional ELU, LDS transpose, 16B stores
    float mk[4];
#pragma unroll
    for (int r = 0; r < 4; ++r) {
        int gr = m0 + w * 16 + q * 4 + r;
        int gi = gr < N_NODES ? gr : N_NODES - 1;
        mk[r] = (gr < N_NODES && deg_inv[gi] > 0.f) ? 1.f : 0.f;
    }
#pragma unroll
    for (int j = 0; j < 8; ++j) {
        float bb = bias[j * 16 + t];
#pragma unroll
        for (int r = 0; r < 4; ++r) {
            float v = acc[j][r] + bb * mk[r];
            if (ELU) v = (v > 0.f) ? v : expm1f(v);
            ys[w][q * 4 + r][j * 16 + t] = v;
        }
    }
    // intra-wave ys write->read (same wave slice), no barrier needed
    for (int i = 0; i < 4; ++i) {
        int c = i * 64 + lane;                 // 256 chunks of 8 floats
        int rowo = c >> 4, seg = c & 15;
        int gr = m0 + w * 16 + rowo;
        if (gr < N_NODES) {
            const float* src = &ys[w][rowo][seg * 8];
            f32x4 a4 = *(const f32x4*)src;
            f32x4 b4 = *(const f32x4*)(src + 4);
            if (OUT_F32) {
                float* of = &((float*)out)[(size_t)gr * F + seg * 8];
                __builtin_nontemporal_store(a4, (f32x4*)of);
                __builtin_nontemporal_store(b4, (f32x4*)(of + 4));
            } else {
                uint4 o = {pkrtz(a4.x, a4.y), pkrtz(a4.z, a4.w), pkrtz(b4.x, b4.y), pkrtz(b4.z, b4.w)};
                *(uint4*)&((ushort*)out)[(size_t)gr * F + seg * 8] = o;
            }
        }
    }
}

// ---------------- launch ----------------

extern "C" void kernel_launch(void* const* d_in, const int* in_sizes, int n_in,
                              void* d_out, int out_size, void* d_ws, size_t ws_size,
                              hipStream_t stream) {
    const float* x  = (const float*)d_in[0];
    const int*   ei = (const int*)d_in[1];
    const float* W1 = (const float*)d_in[2];
    const float* b1 = (const float*)d_in[3];
    const float* W2 = (const float*)d_in[4];
    const float* b2 = (const float*)d_in[5];
    float* out = (float*)d_out;

    const int* row = ei;
    const int* col = ei + N_EDGES;

    // workspace layout (16B-aligned)
    ushort* bufA = (ushort*)d_ws;                            // N*F f16 (h1, 25.6 MB)
    ushort* bufB = bufA + (size_t)N_NODES * F;               // N*F f16 (Xh)
    int* csr_col = (int*)(bufB + (size_t)N_NODES * F);       // NBUCK*CAP (7.2 MB)
    int2* rs = (int2*)(csr_col + NBUCK * CAP);               // N {start,deg}
    float* deg_inv = (float*)(rs + N_NODES + 4);             // N
    int* bucket_cursor = (int*)(deg_inv + N_NODES);          // 256
    uint* W1h = (uint*)(bucket_cursor + 256);                // 8192 uints
    uint* W2h = W1h + F * F / 2;                             // 8192 uints
    int* pairs = (int*)bufA;  // 7.2 MB overlay, dead before fused layer 1 writes bufA

    // CSR build
    (void)hipMemsetAsync(bucket_cursor, 0, NBUCK * sizeof(int), stream);
    bucketize_kernel<<<(N_EDGES + EPB - 1) / EPB, 256, 0, stream>>>(row, col, bucket_cursor, pairs);
    csr_finalize_kernel<<<NBUCK, 512, 0, stream>>>(pairs, bucket_cursor, csr_col, rs, deg_inv);

    convert_w_kernel<<<32, 256, 0, stream>>>(W1, W2, W1h, W2h);
    convert_x_kernel<<<N_NODES * F / 8 / 256, 256, 0, stream>>>(x, (uint*)bufB);

    const int fb = (N_NODES + 63) / 64;   // 1563
    // layer 1: h1 = elu( agg(Xh) @ W1^T + mask*b1 ), f16 out
    fused_agg_gemm_kernel<true, false><<<fb, 256, 0, stream>>>(
        (const ushort*)bufB, rs, csr_col, deg_inv, (const ushort*)W1h, b1, bufA);
    // layer 2: out = agg(h1) @ W2^T + mask*b2, f32 out
    fused_agg_gemm_kernel<false, true><<<fb, 256, 0, stream>>>(
        bufA, rs, csr_col, deg_inv, (const ushort*)W2h, b2, out);
}

// Round 3
// 338.986 us; speedup vs baseline: 1.0077x; 1.0077x over previous
//
#include <hip/hip_runtime.h>
#include <math.h>

#define N_NODES 100000
#define N_EDGES 1600000
#define F 128
#define NBUCK 196        // buckets of 512 rows
#define EPB 4096         // edges per bucketize block
#define CAP 9216         // fixed bucket region capacity (avg 8192, +11 sigma)

typedef _Float16 f16x2 __attribute__((ext_vector_type(2)));
typedef _Float16 f16x8 __attribute__((ext_vector_type(8)));
typedef __fp16 fp16x2 __attribute__((ext_vector_type(2)));
typedef float f32x2 __attribute__((ext_vector_type(2)));
typedef float f32x4 __attribute__((ext_vector_type(4)));

__device__ inline uint pkrtz(float a, float b) {
    union { fp16x2 h; uint u; } c;
    c.h = __builtin_amdgcn_cvt_pkrtz(a, b);
    return c.u;
}
__device__ inline f16x2 as2(uint u) {
    union { uint u; f16x2 h; } c; c.u = u; return c.h;
}

__device__ inline int wave_incl_scan(int v, int lane) {
#pragma unroll
    for (int off = 1; off < 64; off <<= 1) {
        int t = __shfl_up(v, off);
        if (lane >= off) v += t;
    }
    return v;
}

// ---------------- CSR build: single-pass bucket sort, fixed regions ----------------

__global__ __launch_bounds__(256) void bucketize_kernel(const int* __restrict__ row,
                                                        const int* __restrict__ col,
                                                        int* __restrict__ bucket_cursor,
                                                        int* __restrict__ pairs) {
    __shared__ int stage[EPB];
    __shared__ unsigned char bid[EPB];
    __shared__ int lcnt[NBUCK], lcur[NBUCK], loff[NBUCK], gbase[NBUCK];
    __shared__ int wsum[4];
    const int tid = threadIdx.x;
    const int lane = tid & 63;
    const int wid = tid >> 6;
    const int base = blockIdx.x * EPB;
    const int cnt = min(N_EDGES - base, EPB);

    for (int i = tid; i < NBUCK; i += 256) { lcnt[i] = 0; lcur[i] = 0; }
    __syncthreads();
    for (int i = 0; i < EPB / 256; ++i) {
        int e = base + i * 256 + tid;
        if (e < N_EDGES) atomicAdd(&lcnt[row[e] >> 9], 1);
    }
    __syncthreads();
    {   // exclusive scan of lcnt -> loff (wave scan + 4-wave combine)
        int v = (tid < NBUCK) ? lcnt[tid] : 0;
        int inc = wave_incl_scan(v, lane);
        if (lane == 63) wsum[wid] = inc;
        __syncthreads();
        if (tid == 0) {
            int a = 0;
#pragma unroll
            for (int i = 0; i < 4; ++i) { int t = wsum[i]; wsum[i] = a; a += t; }
        }
        __syncthreads();
        if (tid < NBUCK) loff[tid] = inc - v + wsum[wid];
    }
    if (tid < NBUCK) {
        int c = lcnt[tid];
        gbase[tid] = c ? atomicAdd(&bucket_cursor[tid], c) : 0;
    }
    __syncthreads();
    for (int i = 0; i < EPB / 256; ++i) {
        int e = base + i * 256 + tid;
        if (e < N_EDGES) {
            int r = row[e], c = col[e];
            int b = r >> 9;
            int rk = atomicAdd(&lcur[b], 1);
            int q = loff[b] + rk;
            stage[q] = ((r & 511) << 17) | c;   // 9b local row | 17b col
            bid[q] = (unsigned char)b;
        }
    }
    __syncthreads();
    for (int q = tid; q < cnt; q += 256) {
        int b = bid[q];
        int t = gbase[b] + (q - loff[b]);
        if (t < CAP) pairs[b * CAP + t] = stage[q];
    }
}

__global__ __launch_bounds__(512) void csr_finalize_kernel(const int* __restrict__ pairs,
                                                           const int* __restrict__ bucket_cursor,
                                                           int* __restrict__ csr_col,
                                                           int2* __restrict__ rs,
                                                           float* __restrict__ deg_inv) {
    __shared__ int rcnt[512], rcnt2[512], roff[512];
    __shared__ int colstage[CAP];
    __shared__ int wsum[8];
    const int tid = threadIdx.x;
    const int lane = tid & 63;
    const int wid = tid >> 6;
    const int b = blockIdx.x;
    const int cnt = min(bucket_cursor[b], CAP);
    const int base = b * CAP;
    const int* reg = &pairs[base];

    rcnt[tid] = 0;
    rcnt2[tid] = 0;
    __syncthreads();
    for (int q = tid; q < cnt; q += 512) atomicAdd(&rcnt[reg[q] >> 17], 1);
    __syncthreads();
    const int d = rcnt[tid];
    int inc = wave_incl_scan(d, lane);
    if (lane == 63) wsum[wid] = inc;
    __syncthreads();
    if (tid == 0) {
        int a = 0;
#pragma unroll
        for (int i = 0; i < 8; ++i) { int t = wsum[i]; wsum[i] = a; a += t; }
    }
    __syncthreads();
    const int excl = inc - d + wsum[wid];
    roff[tid] = excl;
    const int grow = (b << 9) + tid;
    if (grow < N_NODES) {
        rs[grow] = make_int2(base + excl, d);
        deg_inv[grow] = d ? 1.0f / (float)d : 0.0f;
    }
    __syncthreads();
    for (int q = tid; q < cnt; q += 512) {
        int v = reg[q];
        int lr = v >> 17;
        int rk = atomicAdd(&rcnt2[lr], 1);
        colstage[roff[lr] + rk] = v & 0x1FFFF;
    }
    __syncthreads();
    for (int q = tid; q < cnt; q += 512) csr_col[base + q] = colstage[q];
}

// ---------------- conversions ----------------

__global__ __launch_bounds__(256) void convert_w_kernel(const float* __restrict__ W1,
                                                        const float* __restrict__ W2,
                                                        uint* __restrict__ W1h,
                                                        uint* __restrict__ W2h) {
    int i = blockIdx.x * 256 + threadIdx.x;   // pair index
    if (i < F * F / 2) {
        float2 a = *(const float2*)&W1[i * 2];
        float2 b = *(const float2*)&W2[i * 2];
        W1h[i] = pkrtz(a.x, a.y);
        W2h[i] = pkrtz(b.x, b.y);
    }
}

// X f32 -> f16, 8 floats per thread
__global__ __launch_bounds__(256) void convert_x_kernel(const float* __restrict__ X,
                                                        uint* __restrict__ Xh) {
    int i = blockIdx.x * 256 + threadIdx.x;   // chunk of 8 floats
    if (i < N_NODES * F / 8) {
        float4 a = *(const float4*)&X[(size_t)i * 8];
        float4 b = *(const float4*)&X[(size_t)i * 8 + 4];
        uint4 o = {pkrtz(a.x, a.y), pkrtz(a.z, a.w), pkrtz(b.x, b.y), pkrtz(b.z, b.w)};
        *(uint4*)&Xh[(size_t)i * 4] = o;
    }
}

// ---------------- fused mean-agg + MFMA GEMM (barrier-free) ----------------
// Legality: D^-1 A (H W^T + 1 b^T) = (D^-1 A H) W^T + mask.b^T  (mask = deg>0).
// Block = 256 thr = 4 waves = 64 output rows; wave w owns EXACTLY rows
// 16w..16w+15 of xs (writes them in phase A, reads only them in phase B) ->
// intra-wave LDS ordering, ZERO __syncthreads in the kernel.
// R2 post-mortem: the ys f32 transpose buffer (33.8 KB LDS union) capped
// residency at 4 blk/CU -> occupancy 32%, gather BW 2.1 TB/s. Fix: swap MFMA
// operands (Y^T = W * g^T; A/B frags have identical lane layouts) so lane
// (q,t) holds Y[node=m0+16w+t][feat=16j+4q+r] -> 4 consecutive feats per
// lane -> direct register stores (uint2 f16 / f32x4), no transpose, no ys,
// LDS 17.4 KB -> 8 blk/CU.

template <bool ELU, bool OUT_F32>
__global__ __launch_bounds__(256, 6) void fused_agg_gemm_kernel(
        const ushort* __restrict__ H,
        const int2* __restrict__ rs,
        const int* __restrict__ csr_col,
        const float* __restrict__ deg_inv,
        const ushort* __restrict__ Wh,
        const float* __restrict__ bias,
        void* __restrict__ out) {
    __shared__ __align__(16) ushort xs[64 * 136];    // agg rows, f16, pitch 136

    const int tid = threadIdx.x;
    const int m0 = blockIdx.x << 6;
    const int qw = tid >> 4;          // quarter-wave id 0..15
    const int fo = (tid & 15) << 3;   // ushort feature offset (8 f16 per lane)

    // ---- phase A: gather-aggregate 4 rows per quarter-wave ----
    for (int rr = 0; rr < 4; ++rr) {
        const int rowi = qw * 4 + rr;
        const int node = m0 + rowi;
        f32x2 a[4];
#pragma unroll
        for (int i = 0; i < 4; ++i) a[i] = (f32x2){0.f, 0.f};
        float di = 0.f;
        if (node < N_NODES) {
            const int2 sd = rs[node];
            int p = sd.x;
            const int e = sd.x + sd.y;
            di = deg_inv[node];
            while (p + 7 < e) {   // 8-edge batch: 8 cols, then 8 rows in flight
                int cc[8];
#pragma unroll
                for (int k = 0; k < 8; ++k) cc[k] = __builtin_nontemporal_load(&csr_col[p + k]);
                uint4 vv[8];
#pragma unroll
                for (int k = 0; k < 8; ++k) vv[k] = *(const uint4*)&H[(size_t)cc[k] * F + fo];
#pragma unroll
                for (int k = 0; k < 8; k += 4) {
                    f16x2 h0 = (as2(vv[k].x) + as2(vv[k + 1].x)) + (as2(vv[k + 2].x) + as2(vv[k + 3].x));
                    f16x2 h1 = (as2(vv[k].y) + as2(vv[k + 1].y)) + (as2(vv[k + 2].y) + as2(vv[k + 3].y));
                    f16x2 h2 = (as2(vv[k].z) + as2(vv[k + 1].z)) + (as2(vv[k + 2].z) + as2(vv[k + 3].z));
                    f16x2 h3 = (as2(vv[k].w) + as2(vv[k + 1].w)) + (as2(vv[k + 2].w) + as2(vv[k + 3].w));
                    a[0] += (f32x2){(float)h0.x, (float)h0.y};
                    a[1] += (f32x2){(float)h1.x, (float)h1.y};
                    a[2] += (f32x2){(float)h2.x, (float)h2.y};
                    a[3] += (f32x2){(float)h3.x, (float)h3.y};
                }
                p += 8;
            }
            if (p + 3 < e) {
                int c0 = csr_col[p], c1 = csr_col[p + 1], c2 = csr_col[p + 2], c3 = csr_col[p + 3];
                uint4 v0 = *(const uint4*)&H[(size_t)c0 * F + fo];
                uint4 v1 = *(const uint4*)&H[(size_t)c1 * F + fo];
                uint4 v2 = *(const uint4*)&H[(size_t)c2 * F + fo];
                uint4 v3 = *(const uint4*)&H[(size_t)c3 * F + fo];
                f16x2 h0 = (as2(v0.x) + as2(v1.x)) + (as2(v2.x) + as2(v3.x));
                f16x2 h1 = (as2(v0.y) + as2(v1.y)) + (as2(v2.y) + as2(v3.y));
                f16x2 h2 = (as2(v0.z) + as2(v1.z)) + (as2(v2.z) + as2(v3.z));
                f16x2 h3 = (as2(v0.w) + as2(v1.w)) + (as2(v2.w) + as2(v3.w));
                a[0] += (f32x2){(float)h0.x, (float)h0.y};
                a[1] += (f32x2){(float)h1.x, (float)h1.y};
                a[2] += (f32x2){(float)h2.x, (float)h2.y};
                a[3] += (f32x2){(float)h3.x, (float)h3.y};
                p += 4;
            }
            if (p + 1 < e) {
                int c0 = csr_col[p], c1 = csr_col[p + 1];
                uint4 v0 = *(const uint4*)&H[(size_t)c0 * F + fo];
                uint4 v1 = *(const uint4*)&H[(size_t)c1 * F + fo];
                f16x2 h0 = as2(v0.x) + as2(v1.x);
                f16x2 h1 = as2(v0.y) + as2(v1.y);
                f16x2 h2 = as2(v0.z) + as2(v1.z);
                f16x2 h3 = as2(v0.w) + as2(v1.w);
                a[0] += (f32x2){(float)h0.x, (float)h0.y};
                a[1] += (f32x2){(float)h1.x, (float)h1.y};
                a[2] += (f32x2){(float)h2.x, (float)h2.y};
                a[3] += (f32x2){(float)h3.x, (float)h3.y};
                p += 2;
            }
            if (p < e) {
                int c = csr_col[p];
                uint4 v = *(const uint4*)&H[(size_t)c * F + fo];
                f16x2 h0 = as2(v.x), h1 = as2(v.y), h2 = as2(v.z), h3 = as2(v.w);
                a[0] += (f32x2){(float)h0.x, (float)h0.y};
                a[1] += (f32x2){(float)h1.x, (float)h1.y};
                a[2] += (f32x2){(float)h2.x, (float)h2.y};
                a[3] += (f32x2){(float)h3.x, (float)h3.y};
            }
        }
        uint4 o = {pkrtz(a[0].x * di, a[0].y * di), pkrtz(a[1].x * di, a[1].y * di),
                   pkrtz(a[2].x * di, a[2].y * di), pkrtz(a[3].x * di, a[3].y * di)};
        *(uint4*)&xs[rowi * 136 + fo] = o;
    }
    // NO barrier: wave w wrote rows 16w..16w+15 and reads only those below.

    // ---- phase B: MFMA Y^T = W @ g^T ----
    // A-frag = W rows (out-features), B-frag = xs rows (nodes); identical lane
    // layouts -> D: lane(q,t) reg r = Y[m0+16w+t][16j+4q+r].
    const int w = tid >> 6;
    const int lane = tid & 63;
    const int q = lane >> 4;
    const int t = lane & 15;

    f16x8 xfr[4];
#pragma unroll
    for (int kk = 0; kk < 4; ++kk)
        xfr[kk] = *(const f16x8*)&xs[(w * 16 + t) * 136 + kk * 32 + q * 8];

    f32x4 acc[8];
#pragma unroll
    for (int j = 0; j < 8; ++j) acc[j] = (f32x4){0.f, 0.f, 0.f, 0.f};

#pragma unroll
    for (int j = 0; j < 8; ++j) {
        const ushort* wrow = &Wh[(j * 16 + t) * F + q * 8];
#pragma unroll
        for (int kk = 0; kk < 4; ++kk) {
            f16x8 wfr = *(const f16x8*)&wrow[kk * 32];
            acc[j] = __builtin_amdgcn_mfma_f32_16x16x32_f16(wfr, xfr[kk], acc[j], 0, 0, 0);
        }
    }

    // ---- epilogue: masked bias, optional ELU, direct register stores ----
    const int node = m0 + (w << 4) + t;
    const bool ok = node < N_NODES;
    const float dv = deg_inv[ok ? node : 0];
    const float mk = (ok && dv > 0.f) ? 1.f : 0.f;

#pragma unroll
    for (int j = 0; j < 8; ++j) {
        f32x4 bb = *(const f32x4*)&bias[j * 16 + q * 4];
        f32x4 v = acc[j] + bb * mk;
        if (ELU) {
#pragma unroll
            for (int r = 0; r < 4; ++r) v[r] = (v[r] > 0.f) ? v[r] : expm1f(v[r]);
        }
        if (ok) {
            if (OUT_F32) {
                float* of = &((float*)out)[(size_t)node * F + j * 16 + q * 4];
                __builtin_nontemporal_store(v, (f32x4*)of);
            } else {
                uint2 o = {pkrtz(v[0], v[1]), pkrtz(v[2], v[3])};
                *(uint2*)&((ushort*)out)[(size_t)node * F + j * 16 + q * 4] = o;
            }
        }
    }
}

// ---------------- launch ----------------

extern "C" void kernel_launch(void* const* d_in, const int* in_sizes, int n_in,
                              void* d_out, int out_size, void* d_ws, size_t ws_size,
                              hipStream_t stream) {
    const float* x  = (const float*)d_in[0];
    const int*   ei = (const int*)d_in[1];
    const float* W1 = (const float*)d_in[2];
    const float* b1 = (const float*)d_in[3];
    const float* W2 = (const float*)d_in[4];
    const float* b2 = (const float*)d_in[5];
    float* out = (float*)d_out;

    const int* row = ei;
    const int* col = ei + N_EDGES;

    // workspace layout (16B-aligned)
    ushort* bufA = (ushort*)d_ws;                            // N*F f16 (h1, 25.6 MB)
    ushort* bufB = bufA + (size_t)N_NODES * F;               // N*F f16 (Xh)
    int* csr_col = (int*)(bufB + (size_t)N_NODES * F);       // NBUCK*CAP (7.2 MB)
    int2* rs = (int2*)(csr_col + NBUCK * CAP);               // N {start,deg}
    float* deg_inv = (float*)(rs + N_NODES + 4);             // N
    int* bucket_cursor = (int*)(deg_inv + N_NODES);          // 256
    uint* W1h = (uint*)(bucket_cursor + 256);                // 8192 uints
    uint* W2h = W1h + F * F / 2;                             // 8192 uints
    int* pairs = (int*)bufA;  // 7.2 MB overlay, dead before fused layer 1 writes bufA

    // CSR build
    (void)hipMemsetAsync(bucket_cursor, 0, NBUCK * sizeof(int), stream);
    bucketize_kernel<<<(N_EDGES + EPB - 1) / EPB, 256, 0, stream>>>(row, col, bucket_cursor, pairs);
    csr_finalize_kernel<<<NBUCK, 512, 0, stream>>>(pairs, bucket_cursor, csr_col, rs, deg_inv);

    convert_w_kernel<<<32, 256, 0, stream>>>(W1, W2, W1h, W2h);
    convert_x_kernel<<<N_NODES * F / 8 / 256, 256, 0, stream>>>(x, (uint*)bufB);

    const int fb = (N_NODES + 63) / 64;   // 1563
    // layer 1: h1 = elu( agg(Xh) @ W1^T + mask*b1 ), f16 out
    fused_agg_gemm_kernel<true, false><<<fb, 256, 0, stream>>>(
        (const ushort*)bufB, rs, csr_col, deg_inv, (const ushort*)W1h, b1, bufA);
    // layer 2: out = agg(h1) @ W2^T + mask*b2, f32 out
    fused_agg_gemm_kernel<false, true><<<fb, 256, 0, stream>>>(
        bufA, rs, csr_col, deg_inv, (const ushort*)W2h, b2, out);
}

// Round 4
// 336.695 us; speedup vs baseline: 1.0146x; 1.0068x over previous
//
#include <hip/hip_runtime.h>
#include <math.h>

#define N_NODES 100000
#define N_EDGES 1600000
#define F 128
#define NBUCK 196        // buckets of 512 rows
#define EPB 1024         // edges per bucketize block (R4: 4096->1024, grid 391->1563)
#define CAP 9216         // fixed bucket region capacity (avg 8192, +11 sigma)

typedef _Float16 f16x2 __attribute__((ext_vector_type(2)));
typedef _Float16 f16x8 __attribute__((ext_vector_type(8)));
typedef __fp16 fp16x2 __attribute__((ext_vector_type(2)));
typedef float f32x2 __attribute__((ext_vector_type(2)));
typedef float f32x4 __attribute__((ext_vector_type(4)));

__device__ inline uint pkrtz(float a, float b) {
    union { fp16x2 h; uint u; } c;
    c.h = __builtin_amdgcn_cvt_pkrtz(a, b);
    return c.u;
}
__device__ inline f16x2 as2(uint u) {
    union { uint u; f16x2 h; } c; c.u = u; return c.h;
}

__device__ inline int wave_incl_scan(int v, int lane) {
#pragma unroll
    for (int off = 1; off < 64; off <<= 1) {
        int t = __shfl_up(v, off);
        if (lane >= off) v += t;
    }
    return v;
}

// ---------------- CSR build: single-pass bucket sort, fixed regions ----------------
// R4: bucketize EPB 1024 (was 4096) -> 1563 blocks (6.1/CU, was 1.5/CU).

__global__ __launch_bounds__(256) void bucketize_kernel(const int* __restrict__ row,
                                                        const int* __restrict__ col,
                                                        int* __restrict__ bucket_cursor,
                                                        int* __restrict__ pairs) {
    __shared__ int stage[EPB];
    __shared__ unsigned char bid[EPB];
    __shared__ int lcnt[NBUCK], lcur[NBUCK], loff[NBUCK], gbase[NBUCK];
    __shared__ int wsum[4];
    const int tid = threadIdx.x;
    const int lane = tid & 63;
    const int wid = tid >> 6;
    const int base = blockIdx.x * EPB;
    const int cnt = min(N_EDGES - base, EPB);

    for (int i = tid; i < NBUCK; i += 256) { lcnt[i] = 0; lcur[i] = 0; }
    __syncthreads();
    for (int i = 0; i < EPB / 256; ++i) {
        int e = base + i * 256 + tid;
        if (e < N_EDGES) atomicAdd(&lcnt[row[e] >> 9], 1);
    }
    __syncthreads();
    {   // exclusive scan of lcnt -> loff (wave scan + 4-wave combine)
        int v = (tid < NBUCK) ? lcnt[tid] : 0;
        int inc = wave_incl_scan(v, lane);
        if (lane == 63) wsum[wid] = inc;
        __syncthreads();
        if (tid == 0) {
            int a = 0;
#pragma unroll
            for (int i = 0; i < 4; ++i) { int t = wsum[i]; wsum[i] = a; a += t; }
        }
        __syncthreads();
        if (tid < NBUCK) loff[tid] = inc - v + wsum[wid];
    }
    if (tid < NBUCK) {
        int c = lcnt[tid];
        gbase[tid] = c ? atomicAdd(&bucket_cursor[tid], c) : 0;
    }
    __syncthreads();
    for (int i = 0; i < EPB / 256; ++i) {
        int e = base + i * 256 + tid;
        if (e < N_EDGES) {
            int r = row[e], c = col[e];
            int b = r >> 9;
            int rk = atomicAdd(&lcur[b], 1);
            int q = loff[b] + rk;
            stage[q] = ((r & 511) << 17) | c;   // 9b local row | 17b col
            bid[q] = (unsigned char)b;
        }
    }
    __syncthreads();
    for (int q = tid; q < cnt; q += 256) {
        int b = bid[q];
        int t = gbase[b] + (q - loff[b]);
        if (t < CAP) pairs[b * CAP + t] = stage[q];
    }
}

// R4: 1024 threads; edge-parallel passes stride 1024, row-indexed parts tid<512.
__global__ __launch_bounds__(1024) void csr_finalize_kernel(const int* __restrict__ pairs,
                                                            const int* __restrict__ bucket_cursor,
                                                            int* __restrict__ csr_col,
                                                            int2* __restrict__ rs,
                                                            float* __restrict__ deg_inv) {
    __shared__ int rcnt[512], rcnt2[512], roff[512];
    __shared__ int colstage[CAP];
    __shared__ int wsum[8];
    const int tid = threadIdx.x;
    const int lane = tid & 63;
    const int wid = tid >> 6;
    const int b = blockIdx.x;
    const int cnt = min(bucket_cursor[b], CAP);
    const int base = b * CAP;
    const int* reg = &pairs[base];

    if (tid < 512) { rcnt[tid] = 0; rcnt2[tid] = 0; }
    __syncthreads();
    for (int q = tid; q < cnt; q += 1024) atomicAdd(&rcnt[reg[q] >> 17], 1);
    __syncthreads();
    int d = 0, inc = 0;
    if (tid < 512) {
        d = rcnt[tid];
        inc = wave_incl_scan(d, lane);
        if (lane == 63) wsum[wid] = inc;
    }
    __syncthreads();
    if (tid == 0) {
        int a = 0;
#pragma unroll
        for (int i = 0; i < 8; ++i) { int t = wsum[i]; wsum[i] = a; a += t; }
    }
    __syncthreads();
    if (tid < 512) {
        const int excl = inc - d + wsum[wid];
        roff[tid] = excl;
        const int grow = (b << 9) + tid;
        if (grow < N_NODES) {
            rs[grow] = make_int2(base + excl, d);
            deg_inv[grow] = d ? 1.0f / (float)d : 0.0f;
        }
    }
    __syncthreads();
    for (int q = tid; q < cnt; q += 1024) {
        int v = reg[q];
        int lr = v >> 17;
        int rk = atomicAdd(&rcnt2[lr], 1);
        colstage[roff[lr] + rk] = v & 0x1FFFF;
    }
    __syncthreads();
    for (int q = tid; q < cnt; q += 1024) csr_col[base + q] = colstage[q];
}

// ---------------- conversions ----------------

__global__ __launch_bounds__(256) void convert_w_kernel(const float* __restrict__ W1,
                                                        const float* __restrict__ W2,
                                                        uint* __restrict__ W1h,
                                                        uint* __restrict__ W2h) {
    int i = blockIdx.x * 256 + threadIdx.x;   // pair index
    if (i < F * F / 2) {
        float2 a = *(const float2*)&W1[i * 2];
        float2 b = *(const float2*)&W2[i * 2];
        W1h[i] = pkrtz(a.x, a.y);
        W2h[i] = pkrtz(b.x, b.y);
    }
}

// X f32 -> f16, 8 floats per thread
__global__ __launch_bounds__(256) void convert_x_kernel(const float* __restrict__ X,
                                                        uint* __restrict__ Xh) {
    int i = blockIdx.x * 256 + threadIdx.x;   // chunk of 8 floats
    if (i < N_NODES * F / 8) {
        float4 a = *(const float4*)&X[(size_t)i * 8];
        float4 b = *(const float4*)&X[(size_t)i * 8 + 4];
        uint4 o = {pkrtz(a.x, a.y), pkrtz(a.z, a.w), pkrtz(b.x, b.y), pkrtz(b.z, b.w)};
        *(uint4*)&Xh[(size_t)i * 4] = o;
    }
}

// ---------------- fused mean-agg + MFMA GEMM (1-wave blocks, barrier-free) ----------------
// Legality: D^-1 A (H W^T + 1 b^T) = (D^-1 A H) W^T + mask.b^T  (mask = deg>0).
// R3 post-mortem: 1563 4-wave blocks vs 8-block/CU capacity -> no backfill
// queue, occupancy decays from 76% to 0 (time-avg 50%), gather BW stuck at
// 2.15 TB/s. Fix: 1-wave (64-thr) blocks owning 16 nodes -> grid 6250 (exact:
// 100000/16), continuous backfill like the old 3.76 TB/s spmm, finer load
// balance, zero bounds checks. LDS 4352 B. Quarter-wave gathers 4 nodes
// serially; wave reads only its own xs rows -> zero __syncthreads.
// MFMA operands swapped (Y^T = W * g^T): lane(q,t) holds Y[m0+t][16j+4q+r]
// -> direct register stores, no transpose buffer.

template <bool ELU, bool OUT_F32>
__global__ __launch_bounds__(64, 8) void fused_agg_gemm_kernel(
        const ushort* __restrict__ H,
        const int2* __restrict__ rs,
        const int* __restrict__ csr_col,
        const float* __restrict__ deg_inv,
        const ushort* __restrict__ Wh,
        const float* __restrict__ bias,
        void* __restrict__ out) {
    __shared__ __align__(16) ushort xs[16 * 136];    // agg rows, f16, pitch 136

    const int tid = threadIdx.x;                      // 0..63 (one wave)
    const int m0 = blockIdx.x << 4;                   // 16 nodes per block
    const int qw = tid >> 4;                          // quarter-wave 0..3
    const int fo = (tid & 15) << 3;                   // ushort feature offset

    // ---- phase A: gather-aggregate 4 rows per quarter-wave ----
    for (int rr = 0; rr < 4; ++rr) {
        const int rowi = qw * 4 + rr;
        const int node = m0 + rowi;                   // always < N_NODES (exact grid)
        f32x2 a[4];
#pragma unroll
        for (int i = 0; i < 4; ++i) a[i] = (f32x2){0.f, 0.f};
        const int2 sd = rs[node];
        int p = sd.x;
        const int e = sd.x + sd.y;
        const float di = deg_inv[node];
        while (p + 7 < e) {   // 8-edge batch: 8 cols, then 8 rows in flight
            int cc[8];
#pragma unroll
            for (int k = 0; k < 8; ++k) cc[k] = __builtin_nontemporal_load(&csr_col[p + k]);
            uint4 vv[8];
#pragma unroll
            for (int k = 0; k < 8; ++k) vv[k] = *(const uint4*)&H[(size_t)cc[k] * F + fo];
#pragma unroll
            for (int k = 0; k < 8; k += 4) {
                f16x2 h0 = (as2(vv[k].x) + as2(vv[k + 1].x)) + (as2(vv[k + 2].x) + as2(vv[k + 3].x));
                f16x2 h1 = (as2(vv[k].y) + as2(vv[k + 1].y)) + (as2(vv[k + 2].y) + as2(vv[k + 3].y));
                f16x2 h2 = (as2(vv[k].z) + as2(vv[k + 1].z)) + (as2(vv[k + 2].z) + as2(vv[k + 3].z));
                f16x2 h3 = (as2(vv[k].w) + as2(vv[k + 1].w)) + (as2(vv[k + 2].w) + as2(vv[k + 3].w));
                a[0] += (f32x2){(float)h0.x, (float)h0.y};
                a[1] += (f32x2){(float)h1.x, (float)h1.y};
                a[2] += (f32x2){(float)h2.x, (float)h2.y};
                a[3] += (f32x2){(float)h3.x, (float)h3.y};
            }
            p += 8;
        }
        if (p + 3 < e) {
            int c0 = csr_col[p], c1 = csr_col[p + 1], c2 = csr_col[p + 2], c3 = csr_col[p + 3];
            uint4 v0 = *(const uint4*)&H[(size_t)c0 * F + fo];
            uint4 v1 = *(const uint4*)&H[(size_t)c1 * F + fo];
            uint4 v2 = *(const uint4*)&H[(size_t)c2 * F + fo];
            uint4 v3 = *(const uint4*)&H[(size_t)c3 * F + fo];
            f16x2 h0 = (as2(v0.x) + as2(v1.x)) + (as2(v2.x) + as2(v3.x));
            f16x2 h1 = (as2(v0.y) + as2(v1.y)) + (as2(v2.y) + as2(v3.y));
            f16x2 h2 = (as2(v0.z) + as2(v1.z)) + (as2(v2.z) + as2(v3.z));
            f16x2 h3 = (as2(v0.w) + as2(v1.w)) + (as2(v2.w) + as2(v3.w));
            a[0] += (f32x2){(float)h0.x, (float)h0.y};
            a[1] += (f32x2){(float)h1.x, (float)h1.y};
            a[2] += (f32x2){(float)h2.x, (float)h2.y};
            a[3] += (f32x2){(float)h3.x, (float)h3.y};
            p += 4;
        }
        if (p + 1 < e) {
            int c0 = csr_col[p], c1 = csr_col[p + 1];
            uint4 v0 = *(const uint4*)&H[(size_t)c0 * F + fo];
            uint4 v1 = *(const uint4*)&H[(size_t)c1 * F + fo];
            f16x2 h0 = as2(v0.x) + as2(v1.x);
            f16x2 h1 = as2(v0.y) + as2(v1.y);
            f16x2 h2 = as2(v0.z) + as2(v1.z);
            f16x2 h3 = as2(v0.w) + as2(v1.w);
            a[0] += (f32x2){(float)h0.x, (float)h0.y};
            a[1] += (f32x2){(float)h1.x, (float)h1.y};
            a[2] += (f32x2){(float)h2.x, (float)h2.y};
            a[3] += (f32x2){(float)h3.x, (float)h3.y};
            p += 2;
        }
        if (p < e) {
            int c = csr_col[p];
            uint4 v = *(const uint4*)&H[(size_t)c * F + fo];
            f16x2 h0 = as2(v.x), h1 = as2(v.y), h2 = as2(v.z), h3 = as2(v.w);
            a[0] += (f32x2){(float)h0.x, (float)h0.y};
            a[1] += (f32x2){(float)h1.x, (float)h1.y};
            a[2] += (f32x2){(float)h2.x, (float)h2.y};
            a[3] += (f32x2){(float)h3.x, (float)h3.y};
        }
        uint4 o = {pkrtz(a[0].x * di, a[0].y * di), pkrtz(a[1].x * di, a[1].y * di),
                   pkrtz(a[2].x * di, a[2].y * di), pkrtz(a[3].x * di, a[3].y * di)};
        *(uint4*)&xs[rowi * 136 + fo] = o;
    }
    // NO barrier: this wave wrote all 16 rows and is the only reader.

    // ---- phase B: MFMA Y^T = W @ g^T ----
    const int q = tid >> 4;        // == qw
    const int t = tid & 15;

    f16x8 xfr[4];
#pragma unroll
    for (int kk = 0; kk < 4; ++kk)
        xfr[kk] = *(const f16x8*)&xs[t * 136 + kk * 32 + q * 8];

    f32x4 acc[8];
#pragma unroll
    for (int j = 0; j < 8; ++j) acc[j] = (f32x4){0.f, 0.f, 0.f, 0.f};

#pragma unroll
    for (int j = 0; j < 8; ++j) {
        const ushort* wrow = &Wh[(j * 16 + t) * F + q * 8];
#pragma unroll
        for (int kk = 0; kk < 4; ++kk) {
            f16x8 wfr = *(const f16x8*)&wrow[kk * 32];
            acc[j] = __builtin_amdgcn_mfma_f32_16x16x32_f16(wfr, xfr[kk], acc[j], 0, 0, 0);
        }
    }

    // ---- epilogue: masked bias, optional ELU, direct register stores ----
    const int node = m0 + t;
    const float dv = deg_inv[node];
    const float mk = (dv > 0.f) ? 1.f : 0.f;

#pragma unroll
    for (int j = 0; j < 8; ++j) {
        f32x4 bb = *(const f32x4*)&bias[j * 16 + q * 4];
        f32x4 v = acc[j] + bb * mk;
        if (ELU) {
#pragma unroll
            for (int r = 0; r < 4; ++r) v[r] = (v[r] > 0.f) ? v[r] : expm1f(v[r]);
        }
        if (OUT_F32) {
            float* of = &((float*)out)[(size_t)node * F + j * 16 + q * 4];
            __builtin_nontemporal_store(v, (f32x4*)of);
        } else {
            uint2 o = {pkrtz(v[0], v[1]), pkrtz(v[2], v[3])};
            *(uint2*)&((ushort*)out)[(size_t)node * F + j * 16 + q * 4] = o;
        }
    }
}

// ---------------- launch ----------------

extern "C" void kernel_launch(void* const* d_in, const int* in_sizes, int n_in,
                              void* d_out, int out_size, void* d_ws, size_t ws_size,
                              hipStream_t stream) {
    const float* x  = (const float*)d_in[0];
    const int*   ei = (const int*)d_in[1];
    const float* W1 = (const float*)d_in[2];
    const float* b1 = (const float*)d_in[3];
    const float* W2 = (const float*)d_in[4];
    const float* b2 = (const float*)d_in[5];
    float* out = (float*)d_out;

    const int* row = ei;
    const int* col = ei + N_EDGES;

    // workspace layout (16B-aligned)
    ushort* bufA = (ushort*)d_ws;                            // N*F f16 (h1, 25.6 MB)
    ushort* bufB = bufA + (size_t)N_NODES * F;               // N*F f16 (Xh)
    int* csr_col = (int*)(bufB + (size_t)N_NODES * F);       // NBUCK*CAP (7.2 MB)
    int2* rs = (int2*)(csr_col + NBUCK * CAP);               // N {start,deg}
    float* deg_inv = (float*)(rs + N_NODES + 4);             // N
    int* bucket_cursor = (int*)(deg_inv + N_NODES);          // 256
    uint* W1h = (uint*)(bucket_cursor + 256);                // 8192 uints
    uint* W2h = W1h + F * F / 2;                             // 8192 uints
    int* pairs = (int*)bufA;  // 7.2 MB overlay, dead before fused layer 1 writes bufA

    // CSR build
    (void)hipMemsetAsync(bucket_cursor, 0, NBUCK * sizeof(int), stream);
    bucketize_kernel<<<(N_EDGES + EPB - 1) / EPB, 256, 0, stream>>>(row, col, bucket_cursor, pairs);
    csr_finalize_kernel<<<NBUCK, 1024, 0, stream>>>(pairs, bucket_cursor, csr_col, rs, deg_inv);

    convert_w_kernel<<<32, 256, 0, stream>>>(W1, W2, W1h, W2h);
    convert_x_kernel<<<N_NODES * F / 8 / 256, 256, 0, stream>>>(x, (uint*)bufB);

    const int fb = N_NODES / 16;   // 6250, exact
    // layer 1: h1 = elu( agg(Xh) @ W1^T + mask*b1 ), f16 out
    fused_agg_gemm_kernel<true, false><<<fb, 64, 0, stream>>>(
        (const ushort*)bufB, rs, csr_col, deg_inv, (const ushort*)W1h, b1, bufA);
    // layer 2: out = agg(h1) @ W2^T + mask*b2, f32 out
    fused_agg_gemm_kernel<false, true><<<fb, 64, 0, stream>>>(
        bufA, rs, csr_col, deg_inv, (const ushort*)W2h, b2, out);
}